// Round 7
// baseline (181.489 us; speedup 1.0000x reference)
//
#include <hip/hip_runtime.h>

// GCN layer: out = ReLU(x @ U^T + segment_sum(x[src], dst) @ V^T)
// x: [50000, 64] f32, src/dst: [1M] i32, U/V: [64, 64] f32, out: [50000, 64] f32
//
// Round 7: L2-resident split gather. x converted to fp16 and split into two
// column halves (3.2 MB each < 4 MB/XCD L2). Two gather passes, each with an
// L2-resident working set; out/x streams use nontemporal accesses and
// edge_src is u16 so they don't evict the resident half.

constexpr int N_NODES = 50000;
constexpr int N_EDGES = 1000000;
constexpr int D = 64;

constexpr int SCAN_ELEMS_PER_BLOCK = 512;
constexpr int SCAN_BLOCKS = (N_NODES + SCAN_ELEMS_PER_BLOCK - 1)
                            / SCAN_ELEMS_PER_BLOCK;        // 98
constexpr int CVT_BLOCKS = (N_NODES * D / 4) / 256;        // 3125
constexpr int QB = (N_EDGES / 4 + 255) / 256;              // 977

// ---------------------------------------------------------------------------
// Fused: x -> fp16 column-halves (blocks [0, CVT_BLOCKS)) and degree+rank
// pack (blocks [CVT_BLOCKS, CVT_BLOCKS+QB)). Independent work, one dispatch.
// packed = (rank<<16) | src  (both < 65536 here).
// ---------------------------------------------------------------------------
__global__ __launch_bounds__(256) void cvt_degree_kernel(
    const float* __restrict__ x, _Float16* __restrict__ xh0,
    _Float16* __restrict__ xh1,
    const int* __restrict__ src, const int* __restrict__ dst,
    int* __restrict__ deg, int* __restrict__ packed)
{
    const int bid = blockIdx.x;
    if (bid < CVT_BLOCKS) {
        const int i = (bid * 256 + threadIdx.x) * 4;       // 4 feats, same half
        const float4 v = *reinterpret_cast<const float4*>(x + i);
        const int n = i >> 6, k = i & 63;
        union { _Float16 h[4]; unsigned long long u; } p;
        p.h[0] = (_Float16)v.x;
        p.h[1] = (_Float16)v.y;
        p.h[2] = (_Float16)v.z;
        p.h[3] = (_Float16)v.w;
        _Float16* dsth = (k >= 32) ? xh1 : xh0;
        *reinterpret_cast<unsigned long long*>(dsth + n * 32 + (k & 31)) = p.u;
        return;
    }
    const int q = (bid - CVT_BLOCKS) * 256 + threadIdx.x;
    const int e = q * 4;
    if (e + 3 < N_EDGES) {
        const int4 d4 = *reinterpret_cast<const int4*>(dst + e);
        const int4 s4 = *reinterpret_cast<const int4*>(src + e);
        int4 p4;
        p4.x = (atomicAdd(&deg[d4.x], 1) << 16) | s4.x;
        p4.y = (atomicAdd(&deg[d4.y], 1) << 16) | s4.y;
        p4.z = (atomicAdd(&deg[d4.z], 1) << 16) | s4.z;
        p4.w = (atomicAdd(&deg[d4.w], 1) << 16) | s4.w;
        *reinterpret_cast<int4*>(packed + e) = p4;
    } else if (e < N_EDGES) {
        for (int i = e; i < N_EDGES; ++i)
            packed[i] = (atomicAdd(&deg[dst[i]], 1) << 16) | src[i];
    }
}

// ---------------------------------------------------------------------------
// Scan 2a: per-block partial sums of deg (512 elems/block).
// ---------------------------------------------------------------------------
__global__ __launch_bounds__(256) void scan_partial_kernel(
    const int* __restrict__ deg, int* __restrict__ block_sums)
{
    __shared__ int red[256];
    const int t = threadIdx.x;
    const int idx = blockIdx.x * SCAN_ELEMS_PER_BLOCK + t * 2;
    int s = 0;
    if (idx < N_NODES)     s += deg[idx];
    if (idx + 1 < N_NODES) s += deg[idx + 1];
    red[t] = s;
    __syncthreads();
    for (int off = 128; off > 0; off >>= 1) {
        if (t < off) red[t] += red[t + off];
        __syncthreads();
    }
    if (t == 0) block_sums[blockIdx.x] = red[0];
}

// ---------------------------------------------------------------------------
// Scan 2b: every block scans the 98 block sums in LDS, then local scan;
// writes row_start and inits cursor (aliases deg).
// ---------------------------------------------------------------------------
__global__ __launch_bounds__(256) void scan_apply_kernel(
    int* deg_cursor, const int* __restrict__ block_sums,
    int* __restrict__ row_start)
{
    __shared__ int sbuf[256];
    __shared__ int bsum[128];
    const int t = threadIdx.x;

    if (t < 128) bsum[t] = (t < SCAN_BLOCKS) ? block_sums[t] : 0;
    __syncthreads();
    for (int off = 1; off < 128; off <<= 1) {
        int u = 0;
        if (t < 128 && t >= off) u = bsum[t - off];
        __syncthreads();
        if (t < 128) bsum[t] += u;
        __syncthreads();
    }
    const int blk_off = (blockIdx.x == 0) ? 0 : bsum[blockIdx.x - 1];
    if (blockIdx.x == 0 && t == 0) row_start[N_NODES] = bsum[127];

    const int idx = blockIdx.x * SCAN_ELEMS_PER_BLOCK + t * 2;
    const int d0 = (idx < N_NODES)     ? deg_cursor[idx]     : 0;
    const int d1 = (idx + 1 < N_NODES) ? deg_cursor[idx + 1] : 0;
    const int ts = d0 + d1;
    sbuf[t] = ts;
    __syncthreads();
    for (int off = 1; off < 256; off <<= 1) {
        const int u = (t >= off) ? sbuf[t - off] : 0;
        __syncthreads();
        sbuf[t] += u;
        __syncthreads();
    }
    const int pre = sbuf[t] - ts + blk_off;
    if (idx < N_NODES)     { row_start[idx] = pre;          deg_cursor[idx] = pre; }
    if (idx + 1 < N_NODES) { row_start[idx + 1] = pre + d0; deg_cursor[idx + 1] = pre + d0; }
}

// ---------------------------------------------------------------------------
// Step 3: atomic-free bucket scatter (u16 sources) via precomputed ranks.
// ---------------------------------------------------------------------------
__global__ __launch_bounds__(256) void fill_pos_kernel(
    const int* __restrict__ dst, const int* __restrict__ packed,
    const int* __restrict__ row_start, unsigned short* __restrict__ esrc)
{
    const int q = blockIdx.x * 256 + threadIdx.x;
    const int e = q * 4;
    if (e + 3 < N_EDGES) {
        const int4 d4 = *reinterpret_cast<const int4*>(dst + e);
        const int4 p4 = *reinterpret_cast<const int4*>(packed + e);
        esrc[row_start[d4.x] + (p4.x >> 16)] = (unsigned short)(p4.x & 0xFFFF);
        esrc[row_start[d4.y] + (p4.y >> 16)] = (unsigned short)(p4.y & 0xFFFF);
        esrc[row_start[d4.z] + (p4.z >> 16)] = (unsigned short)(p4.z & 0xFFFF);
        esrc[row_start[d4.w] + (p4.w >> 16)] = (unsigned short)(p4.w & 0xFFFF);
    } else {
        for (int i = e; i < N_EDGES; ++i) {
            const int p = packed[i];
            esrc[row_start[dst[i]] + (p >> 16)] = (unsigned short)(p & 0xFFFF);
        }
    }
}

// ---------------------------------------------------------------------------
// Pass 1: gather fp16 half-0 (k<32, L2-resident 3.2 MB) + x@U^T (full k) +
// V-partial over k<32. Writes pre-activation to out (nontemporal).
// 512 thr = 8 waves; wave per node. Gather lanes: eo=o>>4 (4 edges/iter),
// fp=o&15 (feature pair); dword load = 2 fp16 feats. shfl_xor(16,32) reduce.
// ---------------------------------------------------------------------------
__global__ __launch_bounds__(512, 8) void pass1_kernel(
    const float* __restrict__ x, const _Float16* __restrict__ xh0,
    const int* __restrict__ row_start, const unsigned short* __restrict__ esrc,
    const float* __restrict__ U, const float* __restrict__ V,
    float* __restrict__ out)
{
    __shared__ float Ut[D][D + 1];     // [k][o]
    __shared__ float Vt0[32][D + 1];   // [k<32][o]
    __shared__ float xr[8][D];         // wave-private x row
    __shared__ float ag[8][32];        // wave-private agg half

    const int t = threadIdx.x, o = t & 63, w = t >> 6;

    for (int i = t; i < D * D; i += 512) Ut[i & 63][i >> 6] = U[i];
    for (int i = t; i < 32 * D; i += 512)
        Vt0[i & 31][i >> 5] = V[(i >> 5) * 64 + (i & 31)];
    __syncthreads();

    const int n = blockIdx.x * 8 + w;       // grid exactly N_NODES/8
    const int rowoff = n * D + o;

    xr[w][o] = __builtin_nontemporal_load(x + rowoff);

    const int beg = row_start[n];
    const int end = row_start[n + 1];
    const int eo = o >> 4, fp = o & 15;

    float a0 = 0.f, a1 = 0.f;
    for (int base = beg; base < end; base += 4) {
        const int ei = base + eo;
        const bool valid = ei < end;
        const int ci = valid ? ei : beg;    // beg<end inside loop: safe
        const int s = (int)esrc[ci];
        union { unsigned u; _Float16 h[2]; } pk;
        pk.u = *reinterpret_cast<const unsigned*>(xh0 + s * 32 + fp * 2);
        if (valid) { a0 += (float)pk.h[0]; a1 += (float)pk.h[1]; }
    }
    a0 += __shfl_xor(a0, 16); a0 += __shfl_xor(a0, 32);
    a1 += __shfl_xor(a1, 16); a1 += __shfl_xor(a1, 32);
    if (o < 16) { ag[w][2 * fp] = a0; ag[w][2 * fp + 1] = a1; }
    // wave-private LDS: in-wave ordering, no block barrier needed.

    float sum = 0.f;
    #pragma unroll
    for (int k4 = 0; k4 < 16; ++k4) {
        const int k = k4 * 4;
        const float4 xq = *reinterpret_cast<const float4*>(&xr[w][k]);
        sum += xq.x * Ut[k + 0][o] + xq.y * Ut[k + 1][o]
             + xq.z * Ut[k + 2][o] + xq.w * Ut[k + 3][o];
    }
    #pragma unroll
    for (int k4 = 0; k4 < 8; ++k4) {
        const int k = k4 * 4;
        const float4 aq = *reinterpret_cast<const float4*>(&ag[w][k]);
        sum += aq.x * Vt0[k + 0][o] + aq.y * Vt0[k + 1][o]
             + aq.z * Vt0[k + 2][o] + aq.w * Vt0[k + 3][o];
    }
    __builtin_nontemporal_store(sum, out + rowoff);   // pre-activation
}

// ---------------------------------------------------------------------------
// Pass 2: gather fp16 half-1 (k>=32), V-partial over k>=32, add to out, ReLU.
// ---------------------------------------------------------------------------
__global__ __launch_bounds__(512, 8) void pass2_kernel(
    const _Float16* __restrict__ xh1,
    const int* __restrict__ row_start, const unsigned short* __restrict__ esrc,
    const float* __restrict__ V, float* __restrict__ out)
{
    __shared__ float Vt1[32][D + 1];   // [k-32][o]
    __shared__ float ag[8][32];

    const int t = threadIdx.x, o = t & 63, w = t >> 6;

    for (int i = t; i < 32 * D; i += 512)
        Vt1[i & 31][i >> 5] = V[(i >> 5) * 64 + 32 + (i & 31)];
    __syncthreads();

    const int n = blockIdx.x * 8 + w;
    const int rowoff = n * D + o;

    const int beg = row_start[n];
    const int end = row_start[n + 1];
    const int eo = o >> 4, fp = o & 15;

    float a0 = 0.f, a1 = 0.f;
    for (int base = beg; base < end; base += 4) {
        const int ei = base + eo;
        const bool valid = ei < end;
        const int ci = valid ? ei : beg;
        const int s = (int)esrc[ci];
        union { unsigned u; _Float16 h[2]; } pk;
        pk.u = *reinterpret_cast<const unsigned*>(xh1 + s * 32 + fp * 2);
        if (valid) { a0 += (float)pk.h[0]; a1 += (float)pk.h[1]; }
    }
    a0 += __shfl_xor(a0, 16); a0 += __shfl_xor(a0, 32);
    a1 += __shfl_xor(a1, 16); a1 += __shfl_xor(a1, 32);
    if (o < 16) { ag[w][2 * fp] = a0; ag[w][2 * fp + 1] = a1; }

    float sum = 0.f;
    #pragma unroll
    for (int k4 = 0; k4 < 8; ++k4) {
        const int k = k4 * 4;
        const float4 aq = *reinterpret_cast<const float4*>(&ag[w][k]);
        sum += aq.x * Vt1[k + 0][o] + aq.y * Vt1[k + 1][o]
             + aq.z * Vt1[k + 2][o] + aq.w * Vt1[k + 3][o];
    }
    const float prev = __builtin_nontemporal_load(out + rowoff);
    __builtin_nontemporal_store(fmaxf(prev + sum, 0.f), out + rowoff);
}

// ---------------------------------------------------------------------------
// Mid fallback: atomic-return fill (u16) + single-pass f32 gather.
// ---------------------------------------------------------------------------
__global__ __launch_bounds__(256) void degree_kernel(
    const int* __restrict__ dst, int* __restrict__ deg)
{
    const int e = (blockIdx.x * 256 + threadIdx.x) * 4;
    if (e + 3 < N_EDGES) {
        const int4 d4 = *reinterpret_cast<const int4*>(dst + e);
        atomicAdd(&deg[d4.x], 1);
        atomicAdd(&deg[d4.y], 1);
        atomicAdd(&deg[d4.z], 1);
        atomicAdd(&deg[d4.w], 1);
    } else if (e < N_EDGES) {
        for (int i = e; i < N_EDGES; ++i) atomicAdd(&deg[dst[i]], 1);
    }
}

__global__ __launch_bounds__(256) void fill_kernel(
    const int* __restrict__ src, const int* __restrict__ dst,
    int* cursor, unsigned short* __restrict__ esrc)
{
    const int e = (blockIdx.x * 256 + threadIdx.x) * 4;
    if (e + 3 < N_EDGES) {
        const int4 d4 = *reinterpret_cast<const int4*>(dst + e);
        const int4 s4 = *reinterpret_cast<const int4*>(src + e);
        esrc[atomicAdd(&cursor[d4.x], 1)] = (unsigned short)s4.x;
        esrc[atomicAdd(&cursor[d4.y], 1)] = (unsigned short)s4.y;
        esrc[atomicAdd(&cursor[d4.z], 1)] = (unsigned short)s4.z;
        esrc[atomicAdd(&cursor[d4.w], 1)] = (unsigned short)s4.w;
    } else if (e < N_EDGES) {
        for (int i = e; i < N_EDGES; ++i)
            esrc[atomicAdd(&cursor[dst[i]], 1)] = (unsigned short)src[i];
    }
}

__global__ __launch_bounds__(512, 8) void csr_gather_gemm_kernel(
    const float* __restrict__ x, const int* __restrict__ row_start,
    const unsigned short* __restrict__ esrc,
    const float* __restrict__ U, const float* __restrict__ V,
    float* __restrict__ out)
{
    __shared__ float Ut[D][D + 1];
    __shared__ float Vt[D][D + 1];
    __shared__ float rows[8][2][D];

    const int t = threadIdx.x, o = t & 63, w = t >> 6;

    for (int i = t; i < D * D; i += 512) {
        Ut[i & 63][i >> 6] = U[i];
        Vt[i & 63][i >> 6] = V[i];
    }
    __syncthreads();

    const int n = blockIdx.x * 8 + w;
    const int rowoff = n * D + o;
    rows[w][0][o] = x[rowoff];

    const int beg = row_start[n], end = row_start[n + 1];
    float acc = 0.f;
    for (int i = beg; i < end; ++i) acc += x[(int)esrc[i] * D + o];
    rows[w][1][o] = acc;

    float sum = 0.f;
    #pragma unroll
    for (int k4 = 0; k4 < D / 4; ++k4) {
        const int k = k4 * 4;
        const float4 xq = *reinterpret_cast<const float4*>(&rows[w][0][k]);
        const float4 aq = *reinterpret_cast<const float4*>(&rows[w][1][k]);
        sum += xq.x * Ut[k + 0][o] + aq.x * Vt[k + 0][o];
        sum += xq.y * Ut[k + 1][o] + aq.y * Vt[k + 1][o];
        sum += xq.z * Ut[k + 2][o] + aq.z * Vt[k + 2][o];
        sum += xq.w * Ut[k + 3][o] + aq.w * Vt[k + 3][o];
    }
    out[rowoff] = fmaxf(sum, 0.f);
}

// ---------------------------------------------------------------------------
// Last-resort fallback: atomic scatter + separate GEMM (no ws needed).
// ---------------------------------------------------------------------------
__global__ __launch_bounds__(256) void scatter_add_kernel(
    const float* __restrict__ x, const int* __restrict__ src,
    const int* __restrict__ dst, float* agg)
{
    const int tid = blockIdx.x * 256 + threadIdx.x;
    const int e = tid >> 4;
    const int qq = (tid & 15) << 2;
    const int s = src[e];
    const int d = dst[e];
    const float4 v = *reinterpret_cast<const float4*>(x + s * D + qq);
    float* a = agg + d * D + qq;
    unsafeAtomicAdd(a + 0, v.x);
    unsafeAtomicAdd(a + 1, v.y);
    unsafeAtomicAdd(a + 2, v.z);
    unsafeAtomicAdd(a + 3, v.w);
}

__global__ __launch_bounds__(256) void gemm_relu_kernel(
    const float* __restrict__ x, const float* agg,
    const float* __restrict__ U, const float* __restrict__ V,
    float* out)
{
    __shared__ float Ut[D][D + 1];
    __shared__ float Vt[D][D + 1];
    __shared__ float xs[4][D][4];
    __shared__ float as[4][D][4];

    const int t = threadIdx.x, o = t & 63, w = t >> 6;

    for (int i = t; i < D * D; i += 256) {
        Ut[i & 63][i >> 6] = U[i];
        Vt[i & 63][i >> 6] = V[i];
    }
    __syncthreads();

    const int nb = blockIdx.x * 16 + w * 4;
    #pragma unroll
    for (int j = 0; j < 4; ++j) {
        const int n = nb + j;
        xs[w][o][j] = x[n * D + o];
        as[w][o][j] = agg[n * D + o];
    }

    float acc0 = 0.f, acc1 = 0.f, acc2 = 0.f, acc3 = 0.f;
    #pragma unroll 16
    for (int k = 0; k < D; ++k) {
        const float u = Ut[k][o];
        const float v = Vt[k][o];
        const float4 xv = *reinterpret_cast<const float4*>(&xs[w][k][0]);
        const float4 av = *reinterpret_cast<const float4*>(&as[w][k][0]);
        acc0 += u * xv.x + v * av.x;
        acc1 += u * xv.y + v * av.y;
        acc2 += u * xv.z + v * av.z;
        acc3 += u * xv.w + v * av.w;
    }

    out[(nb + 0) * D + o] = fmaxf(acc0, 0.f);
    out[(nb + 1) * D + o] = fmaxf(acc1, 0.f);
    out[(nb + 2) * D + o] = fmaxf(acc2, 0.f);
    out[(nb + 3) * D + o] = fmaxf(acc3, 0.f);
}

extern "C" void kernel_launch(void* const* d_in, const int* in_sizes, int n_in,
                              void* d_out, int out_size, void* d_ws, size_t ws_size,
                              hipStream_t stream) {
    const float* x   = (const float*)d_in[0];
    const int*   src = (const int*)d_in[1];
    const int*   dst = (const int*)d_in[2];
    const float* U   = (const float*)d_in[3];
    const float* V   = (const float*)d_in[4];
    float* out = (float*)d_out;

    // ws layout (int units): deg/cursor[50000] | row_start[50001] |
    //   block_sums[98] | pad | esrc u16[1M] (=500000 ints) | packed[1M] |
    //   xh0 fp16[1.6M] (=800000 ints) | xh1 fp16[1.6M]
    const size_t deg_off = 0;
    const size_t rs_off  = (size_t)N_NODES;
    const size_t bs_off  = rs_off + N_NODES + 1;
    const size_t es_off  = (bs_off + SCAN_BLOCKS + 3) & ~(size_t)3;
    const size_t pk_off  = es_off + (size_t)N_EDGES / 2;
    const size_t x0_off  = pk_off + (size_t)N_EDGES;
    const size_t x1_off  = x0_off + (size_t)N_NODES * 32 / 2;
    const size_t mid_bytes  = x0_off * sizeof(int);
    const size_t full_bytes = (x1_off + (size_t)N_NODES * 32 / 2) * sizeof(int);

    if (ws_size >= mid_bytes) {
        int* wsi        = (int*)d_ws;
        int* deg_cur    = wsi + deg_off;
        int* row_start  = wsi + rs_off;
        int* block_sums = wsi + bs_off;
        unsigned short* esrc = (unsigned short*)(wsi + es_off);
        int* packed     = wsi + pk_off;
        _Float16* xh0   = (_Float16*)(wsi + x0_off);
        _Float16* xh1   = (_Float16*)(wsi + x1_off);

        hipMemsetAsync(deg_cur, 0, (size_t)N_NODES * sizeof(int), stream);
        if (ws_size >= full_bytes) {
            cvt_degree_kernel<<<CVT_BLOCKS + QB, 256, 0, stream>>>(
                x, xh0, xh1, src, dst, deg_cur, packed);
            scan_partial_kernel<<<SCAN_BLOCKS, 256, 0, stream>>>(deg_cur, block_sums);
            scan_apply_kernel<<<SCAN_BLOCKS, 256, 0, stream>>>(deg_cur, block_sums, row_start);
            fill_pos_kernel<<<QB, 256, 0, stream>>>(dst, packed, row_start, esrc);
            pass1_kernel<<<N_NODES / 8, 512, 0, stream>>>(
                x, xh0, row_start, esrc, U, V, out);
            pass2_kernel<<<N_NODES / 8, 512, 0, stream>>>(
                xh1, row_start, esrc, V, out);
        } else {
            degree_kernel<<<QB, 256, 0, stream>>>(dst, deg_cur);
            scan_partial_kernel<<<SCAN_BLOCKS, 256, 0, stream>>>(deg_cur, block_sums);
            scan_apply_kernel<<<SCAN_BLOCKS, 256, 0, stream>>>(deg_cur, block_sums, row_start);
            fill_kernel<<<QB, 256, 0, stream>>>(src, dst, deg_cur, esrc);
            csr_gather_gemm_kernel<<<N_NODES / 8, 512, 0, stream>>>(
                x, row_start, esrc, U, V, out);
        }
    } else {
        const size_t agg_bytes = (size_t)N_NODES * D * sizeof(float);
        float* agg = (ws_size >= agg_bytes) ? (float*)d_ws : out;
        hipMemsetAsync(agg, 0, agg_bytes, stream);
        scatter_add_kernel<<<(N_EDGES * 16) / 256, 256, 0, stream>>>(x, src, dst, agg);
        gemm_relu_kernel<<<N_NODES / 16, 256, 0, stream>>>(x, agg, U, V, out);
    }
}

// Round 8
// 136.474 us; speedup vs baseline: 1.3298x; 1.3298x over previous
//
#include <hip/hip_runtime.h>

// GCN layer: out = ReLU(x @ U^T + segment_sum(x[src], dst) @ V^T)
// x: [50000, 64] f32, src/dst: [1M] i32, U/V: [64, 64] f32, out: [50000, 64] f32
//
// Round 8: single-pass fused gather (r5 structure) with register-resident
// edge indices: one wave-load fetches up to 64 u16 indices into lanes;
// row addresses come from __shfl (no memory dependency), row loads issued
// 8-deep. Removes the per-iteration {index-load -> row-load} serial chain
// that r4-r7 profiling showed to be the binder (duration insensitive to
// cache level / byte count; VALUBusy ~47%).

constexpr int N_NODES = 50000;
constexpr int N_EDGES = 1000000;
constexpr int D = 64;

constexpr int SCAN_ELEMS_PER_BLOCK = 512;
constexpr int SCAN_BLOCKS = (N_NODES + SCAN_ELEMS_PER_BLOCK - 1)
                            / SCAN_ELEMS_PER_BLOCK;        // 98
constexpr int CVT_BLOCKS = (N_NODES * D / 4) / 256;        // 3125
constexpr int QB = (N_EDGES / 4 + 255) / 256;              // 977

// ---------------------------------------------------------------------------
// Fused: x -> fp16 (blocks [0, CVT_BLOCKS)) and degree+rank pack
// (blocks [CVT_BLOCKS, CVT_BLOCKS+QB)). packed = (rank<<16) | src.
// ---------------------------------------------------------------------------
__global__ __launch_bounds__(256) void cvt_degree_kernel(
    const float* __restrict__ x, _Float16* __restrict__ xh,
    const int* __restrict__ src, const int* __restrict__ dst,
    int* __restrict__ deg, int* __restrict__ packed)
{
    const int bid = blockIdx.x;
    if (bid < CVT_BLOCKS) {
        const int i = (bid * 256 + threadIdx.x) * 4;
        const float4 v = *reinterpret_cast<const float4*>(x + i);
        union { _Float16 h[4]; unsigned long long u; } p;
        p.h[0] = (_Float16)v.x;
        p.h[1] = (_Float16)v.y;
        p.h[2] = (_Float16)v.z;
        p.h[3] = (_Float16)v.w;
        *reinterpret_cast<unsigned long long*>(xh + i) = p.u;
        return;
    }
    const int q = (bid - CVT_BLOCKS) * 256 + threadIdx.x;
    const int e = q * 4;
    if (e + 3 < N_EDGES) {
        const int4 d4 = *reinterpret_cast<const int4*>(dst + e);
        const int4 s4 = *reinterpret_cast<const int4*>(src + e);
        int4 p4;
        p4.x = (atomicAdd(&deg[d4.x], 1) << 16) | s4.x;
        p4.y = (atomicAdd(&deg[d4.y], 1) << 16) | s4.y;
        p4.z = (atomicAdd(&deg[d4.z], 1) << 16) | s4.z;
        p4.w = (atomicAdd(&deg[d4.w], 1) << 16) | s4.w;
        *reinterpret_cast<int4*>(packed + e) = p4;
    } else if (e < N_EDGES) {
        for (int i = e; i < N_EDGES; ++i)
            packed[i] = (atomicAdd(&deg[dst[i]], 1) << 16) | src[i];
    }
}

// ---------------------------------------------------------------------------
// Scan 2a: per-block partial sums of deg (512 elems/block).
// ---------------------------------------------------------------------------
__global__ __launch_bounds__(256) void scan_partial_kernel(
    const int* __restrict__ deg, int* __restrict__ block_sums)
{
    __shared__ int red[256];
    const int t = threadIdx.x;
    const int idx = blockIdx.x * SCAN_ELEMS_PER_BLOCK + t * 2;
    int s = 0;
    if (idx < N_NODES)     s += deg[idx];
    if (idx + 1 < N_NODES) s += deg[idx + 1];
    red[t] = s;
    __syncthreads();
    for (int off = 128; off > 0; off >>= 1) {
        if (t < off) red[t] += red[t + off];
        __syncthreads();
    }
    if (t == 0) block_sums[blockIdx.x] = red[0];
}

// ---------------------------------------------------------------------------
// Scan 2b: every block scans the 98 block sums in LDS, then local scan;
// writes row_start and inits cursor (aliases deg).
// ---------------------------------------------------------------------------
__global__ __launch_bounds__(256) void scan_apply_kernel(
    int* deg_cursor, const int* __restrict__ block_sums,
    int* __restrict__ row_start)
{
    __shared__ int sbuf[256];
    __shared__ int bsum[128];
    const int t = threadIdx.x;

    if (t < 128) bsum[t] = (t < SCAN_BLOCKS) ? block_sums[t] : 0;
    __syncthreads();
    for (int off = 1; off < 128; off <<= 1) {
        int u = 0;
        if (t < 128 && t >= off) u = bsum[t - off];
        __syncthreads();
        if (t < 128) bsum[t] += u;
        __syncthreads();
    }
    const int blk_off = (blockIdx.x == 0) ? 0 : bsum[blockIdx.x - 1];
    if (blockIdx.x == 0 && t == 0) row_start[N_NODES] = bsum[127];

    const int idx = blockIdx.x * SCAN_ELEMS_PER_BLOCK + t * 2;
    const int d0 = (idx < N_NODES)     ? deg_cursor[idx]     : 0;
    const int d1 = (idx + 1 < N_NODES) ? deg_cursor[idx + 1] : 0;
    const int ts = d0 + d1;
    sbuf[t] = ts;
    __syncthreads();
    for (int off = 1; off < 256; off <<= 1) {
        const int u = (t >= off) ? sbuf[t - off] : 0;
        __syncthreads();
        sbuf[t] += u;
        __syncthreads();
    }
    const int pre = sbuf[t] - ts + blk_off;
    if (idx < N_NODES)     { row_start[idx] = pre;          deg_cursor[idx] = pre; }
    if (idx + 1 < N_NODES) { row_start[idx + 1] = pre + d0; deg_cursor[idx + 1] = pre + d0; }
}

// ---------------------------------------------------------------------------
// Step 3: atomic-free bucket scatter (u16 sources) via precomputed ranks.
// ---------------------------------------------------------------------------
__global__ __launch_bounds__(256) void fill_pos_kernel(
    const int* __restrict__ dst, const int* __restrict__ packed,
    const int* __restrict__ row_start, unsigned short* __restrict__ esrc)
{
    const int q = blockIdx.x * 256 + threadIdx.x;
    const int e = q * 4;
    if (e + 3 < N_EDGES) {
        const int4 d4 = *reinterpret_cast<const int4*>(dst + e);
        const int4 p4 = *reinterpret_cast<const int4*>(packed + e);
        esrc[row_start[d4.x] + (p4.x >> 16)] = (unsigned short)(p4.x & 0xFFFF);
        esrc[row_start[d4.y] + (p4.y >> 16)] = (unsigned short)(p4.y & 0xFFFF);
        esrc[row_start[d4.z] + (p4.z >> 16)] = (unsigned short)(p4.z & 0xFFFF);
        esrc[row_start[d4.w] + (p4.w >> 16)] = (unsigned short)(p4.w & 0xFFFF);
    } else {
        for (int i = e; i < N_EDGES; ++i) {
            const int p = packed[i];
            esrc[row_start[dst[i]] + (p >> 16)] = (unsigned short)(p & 0xFFFF);
        }
    }
}

// ---------------------------------------------------------------------------
// Fused gather + dual-GEMM + ReLU, register-resident indices.
// 512 thr = 8 waves share one Ut/Vt; wave per node; lane = output feature.
// Index prefetch: lane l holds esrc[beg+l] (one wave-load per 64 edges).
// Row loads issued 8-deep with __shfl-derived addresses (no mem dependency).
// ---------------------------------------------------------------------------
__global__ __launch_bounds__(512, 8) void csr_gather_gemm_f16_kernel(
    const float* __restrict__ x, const _Float16* __restrict__ xh,
    const int* __restrict__ row_start, const unsigned short* __restrict__ esrc,
    const float* __restrict__ U, const float* __restrict__ V,
    float* __restrict__ out)
{
    __shared__ float Ut[D][D + 1];
    __shared__ float Vt[D][D + 1];
    __shared__ float rows[8][2][D];   // [wave][x|agg][k]

    const int t = threadIdx.x, o = t & 63, w = t >> 6;

    for (int i = t; i < D * D; i += 512) {
        Ut[i & 63][i >> 6] = U[i];
        Vt[i & 63][i >> 6] = V[i];
    }
    __syncthreads();

    const int n = blockIdx.x * 8 + w;   // grid exactly N_NODES/8
    const int rowoff = n * D + o;

    rows[w][0][o] = x[rowoff];

    const int beg = row_start[n], end = row_start[n + 1];
    float acc = 0.f;

    for (int cb = beg; cb < end; cb += 64) {
        const int cnt = min(end - cb, 64);
        // one wave-load: lane l holds index of edge cb+l
        const int li = cb + ((o < cnt) ? o : 0);
        const int vidx = (int)esrc[li];

        int j = 0;
        for (; j + 8 <= cnt; j += 8) {
            const int s0 = __shfl(vidx, j + 0), s1 = __shfl(vidx, j + 1);
            const int s2 = __shfl(vidx, j + 2), s3 = __shfl(vidx, j + 3);
            const int s4 = __shfl(vidx, j + 4), s5 = __shfl(vidx, j + 5);
            const int s6 = __shfl(vidx, j + 6), s7 = __shfl(vidx, j + 7);
            const float f0 = (float)xh[s0 * D + o];
            const float f1 = (float)xh[s1 * D + o];
            const float f2 = (float)xh[s2 * D + o];
            const float f3 = (float)xh[s3 * D + o];
            const float f4 = (float)xh[s4 * D + o];
            const float f5 = (float)xh[s5 * D + o];
            const float f6 = (float)xh[s6 * D + o];
            const float f7 = (float)xh[s7 * D + o];
            acc += ((f0 + f1) + (f2 + f3)) + ((f4 + f5) + (f6 + f7));
        }
        for (; j + 2 <= cnt; j += 2) {
            const int s0 = __shfl(vidx, j + 0), s1 = __shfl(vidx, j + 1);
            acc += (float)xh[s0 * D + o] + (float)xh[s1 * D + o];
        }
        for (; j < cnt; ++j) {
            const int s = __shfl(vidx, j);
            acc += (float)xh[s * D + o];
        }
    }
    rows[w][1][o] = acc;
    // wave-private LDS rows: in-wave ordering, no block barrier needed.

    float sum = 0.f;
    #pragma unroll
    for (int k4 = 0; k4 < D / 4; ++k4) {
        const int k = k4 * 4;
        const float4 xq = *reinterpret_cast<const float4*>(&rows[w][0][k]);
        const float4 aq = *reinterpret_cast<const float4*>(&rows[w][1][k]);
        sum += xq.x * Ut[k + 0][o] + aq.x * Vt[k + 0][o];
        sum += xq.y * Ut[k + 1][o] + aq.y * Vt[k + 1][o];
        sum += xq.z * Ut[k + 2][o] + aq.z * Vt[k + 2][o];
        sum += xq.w * Ut[k + 3][o] + aq.w * Vt[k + 3][o];
    }
    out[rowoff] = fmaxf(sum, 0.f);
}

// ---------------------------------------------------------------------------
// Mid fallback: atomic-return fill (u16) + single-pass f32 gather.
// ---------------------------------------------------------------------------
__global__ __launch_bounds__(256) void degree_kernel(
    const int* __restrict__ dst, int* __restrict__ deg)
{
    const int e = (blockIdx.x * 256 + threadIdx.x) * 4;
    if (e + 3 < N_EDGES) {
        const int4 d4 = *reinterpret_cast<const int4*>(dst + e);
        atomicAdd(&deg[d4.x], 1);
        atomicAdd(&deg[d4.y], 1);
        atomicAdd(&deg[d4.z], 1);
        atomicAdd(&deg[d4.w], 1);
    } else if (e < N_EDGES) {
        for (int i = e; i < N_EDGES; ++i) atomicAdd(&deg[dst[i]], 1);
    }
}

__global__ __launch_bounds__(256) void fill_kernel(
    const int* __restrict__ src, const int* __restrict__ dst,
    int* cursor, unsigned short* __restrict__ esrc)
{
    const int e = (blockIdx.x * 256 + threadIdx.x) * 4;
    if (e + 3 < N_EDGES) {
        const int4 d4 = *reinterpret_cast<const int4*>(dst + e);
        const int4 s4 = *reinterpret_cast<const int4*>(src + e);
        esrc[atomicAdd(&cursor[d4.x], 1)] = (unsigned short)s4.x;
        esrc[atomicAdd(&cursor[d4.y], 1)] = (unsigned short)s4.y;
        esrc[atomicAdd(&cursor[d4.z], 1)] = (unsigned short)s4.z;
        esrc[atomicAdd(&cursor[d4.w], 1)] = (unsigned short)s4.w;
    } else if (e < N_EDGES) {
        for (int i = e; i < N_EDGES; ++i)
            esrc[atomicAdd(&cursor[dst[i]], 1)] = (unsigned short)src[i];
    }
}

__global__ __launch_bounds__(512, 8) void csr_gather_gemm_kernel(
    const float* __restrict__ x, const int* __restrict__ row_start,
    const unsigned short* __restrict__ esrc,
    const float* __restrict__ U, const float* __restrict__ V,
    float* __restrict__ out)
{
    __shared__ float Ut[D][D + 1];
    __shared__ float Vt[D][D + 1];
    __shared__ float rows[8][2][D];

    const int t = threadIdx.x, o = t & 63, w = t >> 6;

    for (int i = t; i < D * D; i += 512) {
        Ut[i & 63][i >> 6] = U[i];
        Vt[i & 63][i >> 6] = V[i];
    }
    __syncthreads();

    const int n = blockIdx.x * 8 + w;
    const int rowoff = n * D + o;
    rows[w][0][o] = x[rowoff];

    const int beg = row_start[n], end = row_start[n + 1];
    float acc = 0.f;
    for (int i = beg; i < end; ++i) acc += x[(int)esrc[i] * D + o];
    rows[w][1][o] = acc;

    float sum = 0.f;
    #pragma unroll
    for (int k4 = 0; k4 < D / 4; ++k4) {
        const int k = k4 * 4;
        const float4 xq = *reinterpret_cast<const float4*>(&rows[w][0][k]);
        const float4 aq = *reinterpret_cast<const float4*>(&rows[w][1][k]);
        sum += xq.x * Ut[k + 0][o] + aq.x * Vt[k + 0][o];
        sum += xq.y * Ut[k + 1][o] + aq.y * Vt[k + 1][o];
        sum += xq.z * Ut[k + 2][o] + aq.z * Vt[k + 2][o];
        sum += xq.w * Ut[k + 3][o] + aq.w * Vt[k + 3][o];
    }
    out[rowoff] = fmaxf(sum, 0.f);
}

// ---------------------------------------------------------------------------
// Last-resort fallback: atomic scatter + separate GEMM (no ws needed).
// ---------------------------------------------------------------------------
__global__ __launch_bounds__(256) void scatter_add_kernel(
    const float* __restrict__ x, const int* __restrict__ src,
    const int* __restrict__ dst, float* agg)
{
    const int tid = blockIdx.x * 256 + threadIdx.x;
    const int e = tid >> 4;
    const int qq = (tid & 15) << 2;
    const int s = src[e];
    const int d = dst[e];
    const float4 v = *reinterpret_cast<const float4*>(x + s * D + qq);
    float* a = agg + d * D + qq;
    unsafeAtomicAdd(a + 0, v.x);
    unsafeAtomicAdd(a + 1, v.y);
    unsafeAtomicAdd(a + 2, v.z);
    unsafeAtomicAdd(a + 3, v.w);
}

__global__ __launch_bounds__(256) void gemm_relu_kernel(
    const float* __restrict__ x, const float* agg,
    const float* __restrict__ U, const float* __restrict__ V,
    float* out)
{
    __shared__ float Ut[D][D + 1];
    __shared__ float Vt[D][D + 1];
    __shared__ float xs[4][D][4];
    __shared__ float as[4][D][4];

    const int t = threadIdx.x, o = t & 63, w = t >> 6;

    for (int i = t; i < D * D; i += 256) {
        Ut[i & 63][i >> 6] = U[i];
        Vt[i & 63][i >> 6] = V[i];
    }
    __syncthreads();

    const int nb = blockIdx.x * 16 + w * 4;
    #pragma unroll
    for (int j = 0; j < 4; ++j) {
        const int n = nb + j;
        xs[w][o][j] = x[n * D + o];
        as[w][o][j] = agg[n * D + o];
    }

    float acc0 = 0.f, acc1 = 0.f, acc2 = 0.f, acc3 = 0.f;
    #pragma unroll 16
    for (int k = 0; k < D; ++k) {
        const float u = Ut[k][o];
        const float v = Vt[k][o];
        const float4 xv = *reinterpret_cast<const float4*>(&xs[w][k][0]);
        const float4 av = *reinterpret_cast<const float4*>(&as[w][k][0]);
        acc0 += u * xv.x + v * av.x;
        acc1 += u * xv.y + v * av.y;
        acc2 += u * xv.z + v * av.z;
        acc3 += u * xv.w + v * av.w;
    }

    out[(nb + 0) * D + o] = fmaxf(acc0, 0.f);
    out[(nb + 1) * D + o] = fmaxf(acc1, 0.f);
    out[(nb + 2) * D + o] = fmaxf(acc2, 0.f);
    out[(nb + 3) * D + o] = fmaxf(acc3, 0.f);
}

extern "C" void kernel_launch(void* const* d_in, const int* in_sizes, int n_in,
                              void* d_out, int out_size, void* d_ws, size_t ws_size,
                              hipStream_t stream) {
    const float* x   = (const float*)d_in[0];
    const int*   src = (const int*)d_in[1];
    const int*   dst = (const int*)d_in[2];
    const float* U   = (const float*)d_in[3];
    const float* V   = (const float*)d_in[4];
    float* out = (float*)d_out;

    // ws layout (int units): deg/cursor[50000] | row_start[50001] |
    //   block_sums[98] | pad | esrc u16[1M+64 pad] | packed[1M] | xh fp16[3.2M]
    const size_t deg_off = 0;
    const size_t rs_off  = (size_t)N_NODES;
    const size_t bs_off  = rs_off + N_NODES + 1;
    const size_t es_off  = (bs_off + SCAN_BLOCKS + 3) & ~(size_t)3;
    const size_t pk_off  = es_off + (size_t)(N_EDGES + 64) / 2;
    const size_t xh_off  = pk_off + (size_t)N_EDGES;
    const size_t mid_bytes  = pk_off * sizeof(int);
    const size_t full_bytes = (xh_off + (size_t)N_NODES * D / 2) * sizeof(int);

    if (ws_size >= mid_bytes) {
        int* wsi        = (int*)d_ws;
        int* deg_cur    = wsi + deg_off;
        int* row_start  = wsi + rs_off;
        int* block_sums = wsi + bs_off;
        unsigned short* esrc = (unsigned short*)(wsi + es_off);
        int* packed     = wsi + pk_off;
        _Float16* xh    = (_Float16*)(wsi + xh_off);

        hipMemsetAsync(deg_cur, 0, (size_t)N_NODES * sizeof(int), stream);
        if (ws_size >= full_bytes) {
            cvt_degree_kernel<<<CVT_BLOCKS + QB, 256, 0, stream>>>(
                x, xh, src, dst, deg_cur, packed);
            scan_partial_kernel<<<SCAN_BLOCKS, 256, 0, stream>>>(deg_cur, block_sums);
            scan_apply_kernel<<<SCAN_BLOCKS, 256, 0, stream>>>(deg_cur, block_sums, row_start);
            fill_pos_kernel<<<QB, 256, 0, stream>>>(dst, packed, row_start, esrc);
            csr_gather_gemm_f16_kernel<<<N_NODES / 8, 512, 0, stream>>>(
                x, xh, row_start, esrc, U, V, out);
        } else {
            degree_kernel<<<QB, 256, 0, stream>>>(dst, deg_cur);
            scan_partial_kernel<<<SCAN_BLOCKS, 256, 0, stream>>>(deg_cur, block_sums);
            scan_apply_kernel<<<SCAN_BLOCKS, 256, 0, stream>>>(deg_cur, block_sums, row_start);
            fill_kernel<<<QB, 256, 0, stream>>>(src, dst, deg_cur, esrc);
            csr_gather_gemm_kernel<<<N_NODES / 8, 512, 0, stream>>>(
                x, row_start, esrc, U, V, out);
        }
    } else {
        const size_t agg_bytes = (size_t)N_NODES * D * sizeof(float);
        float* agg = (ws_size >= agg_bytes) ? (float*)d_ws : out;
        hipMemsetAsync(agg, 0, agg_bytes, stream);
        scatter_add_kernel<<<(N_EDGES * 16) / 256, 256, 0, stream>>>(x, src, dst, agg);
        gemm_relu_kernel<<<N_NODES / 16, 256, 0, stream>>>(x, agg, U, V, out);
    }
}